// Round 9
// baseline (2061.538 us; speedup 1.0000x reference)
//
#include <hip/hip_runtime.h>
#include <hip/hip_bf16.h>
#include <stdint.h>

#define LL 512
#define BB 64
#define CC 512
#define TM 255   // meeting point: fwd covers emits 0..255, bwd covers 256..511

typedef float float4v __attribute__((ext_vector_type(4)));
typedef int   int4v   __attribute__((ext_vector_type(4)));
typedef unsigned int uint4v __attribute__((ext_vector_type(4)));
typedef int   int8v  __attribute__((ext_vector_type(8)));

// ws layout (bytes)
#define WS_ET     262144   // E^T fp8 (E fwd fp8 at 0)
#define WS_SCORE  524288   // f32 (zeroed by prep)
#define WS_SVA    524352   // 64 f32
#define WS_SVB    524608   // 64 f32
#define WS_ALPHA  528384   // 64*512 f32 (class-ordered)
#define WS_BETA   659456   // 64*512 f32 (class-ordered)

// position permutation shared by p8 rows and E/E^T columns:
//   column n lives at row-byte (n>>6)*64 + (n&15)*4 + ((n>>4)&3)
//
// normalization (pow2): stored S_t = quant(v_t * 2^-g_t), v_t = MFMA(S_{t-1})*ex_t,
//   g_t = floor(log2(M'_{t-1})) + 6,  M'_{t-1} = max(stored S_{t-1})
//   M' tracking atomic-free: wave writes its 16 row-maxes to mslotW[t&1][wv][chain];
//   consumer u32-maxes the 16 wave slots. true alpha_t = S_t * D_t, logD = gsum*ln2.
//
// 16-wave version: each wave owns 32 output columns (2 col-groups); E fragments are
// re-loaded from L2 each step (NOT register-resident) so VGPR <= 128 -> 4 waves/SIMD.

__device__ __forceinline__ bool mask_at(const void* maskp, bool is_byte, int t, int b) {
    if (is_byte) return ((const unsigned char*)maskp)[t * BB + b] != 0;
    return ((const int*)maskp)[t * BB + b] != 0;
}

__device__ __forceinline__ float rowmax16_dpp(float x) {
    int t;
    t = __builtin_amdgcn_update_dpp(0, __float_as_int(x), 0x128, 0xF, 0xF, true); // ror:8
    x = fmaxf(x, __int_as_float(t));
    t = __builtin_amdgcn_update_dpp(0, __float_as_int(x), 0x124, 0xF, 0xF, true); // ror:4
    x = fmaxf(x, __int_as_float(t));
    t = __builtin_amdgcn_update_dpp(0, __float_as_int(x), 0x122, 0xF, 0xF, true); // ror:2
    x = fmaxf(x, __int_as_float(t));
    t = __builtin_amdgcn_update_dpp(0, __float_as_int(x), 0x121, 0xF, 0xF, true); // ror:1
    x = fmaxf(x, __int_as_float(t));
    return x;
}

// LDS-exchange barrier WITHOUT vmcnt drain: global prefetches stay in flight.
__device__ __forceinline__ void step_barrier() {
    asm volatile("s_waitcnt lgkmcnt(0)" ::: "memory");
    __builtin_amdgcn_sched_barrier(0);
    __builtin_amdgcn_s_barrier();
    asm volatile("" ::: "memory");
}

// E (fwd) and E^T (bwd) in fp8, permuted layout. Also zero the score slot.
__global__ void prep_kernel(const float* __restrict__ trans, unsigned char* __restrict__ ws) {
    int g = blockIdx.x * blockDim.x + threadIdx.x;
    if (g == 0) *(float*)(ws + WS_SCORE) = 0.0f;
    if (g >= 512 * 128) return;
    int n  = g & 511;
    int pd = g >> 9;
    int wv = pd >> 4, rw = pd & 15;
    float f[4], ft[4];
#pragma unroll
    for (int nt = 0; nt < 4; ++nt) {
        int k = 64 * wv + 16 * nt + rw;
        f[nt]  = __expf(trans[(size_t)k * CC + n]);   // E[k][n]
        ft[nt] = __expf(trans[(size_t)n * CC + k]);   // E[n][k]
    }
    int r = 0;
    r = __builtin_amdgcn_cvt_pk_fp8_f32(f[0], f[1], r, false);
    r = __builtin_amdgcn_cvt_pk_fp8_f32(f[2], f[3], r, true);
    ((int*)ws)[n * 128 + pd] = r;
    int r2 = 0;
    r2 = __builtin_amdgcn_cvt_pk_fp8_f32(ft[0], ft[1], r2, false);
    r2 = __builtin_amdgcn_cvt_pk_fp8_f32(ft[2], ft[3], r2, true);
    ((int*)(ws + WS_ET))[n * 128 + pd] = r2;
}

// blocks 0..3: fwd alpha t=1..255; blocks 4..7: bwd beta t=510..255; blocks 8..39: score
__launch_bounds__(1024, 4)
__global__ void crf_scan_kernel(const float* __restrict__ emit,
                                const int* __restrict__ target,
                                const void* __restrict__ maskp,
                                const float* __restrict__ trans,
                                const float* __restrict__ tfs,
                                const float* __restrict__ t2e,
                                unsigned char* __restrict__ ws) {
    const int tid = threadIdx.x;
    const bool is_byte = ((const unsigned char*)maskp)[1] != 0;

    if (blockIdx.x >= 8) {   // -------- score part --------
        int sb = blockIdx.x - 8;
        float val = 0.0f;
        for (int e = sb * 1024 + tid; e < LL * BB; e += 32 * 1024) {
            int t = e >> 6, b = e & 63;
            if (mask_at(maskp, is_byte, t, b)) {
                int tg  = target[t * BB + b];
                float v = emit[(size_t)(t * BB + b) * CC + tg];
                if (t > 0) v += trans[(size_t)target[(t - 1) * BB + b] * CC + tg];
                val += v;
            }
        }
        if (sb == 0 && tid < BB) {
            int b = tid;
            val += tfs[target[b]];
            int lo = 0, hi = LL;
            while (lo < hi) {
                int mid = (lo + hi) >> 1;
                if (mask_at(maskp, is_byte, mid, b)) lo = mid + 1; else hi = mid;
            }
            val += t2e[target[(lo - 1) * BB + b]];
        }
        for (int off = 32; off > 0; off >>= 1) val += __shfl_down(val, off);
        if ((tid & 63) == 0) atomicAdd((float*)(ws + WS_SCORE), val);
        return;
    }

    const bool is_fwd = blockIdx.x < 4;
    const int B0 = (is_fwd ? blockIdx.x : blockIdx.x - 4) * 16;

    __shared__ __align__(16) unsigned char p8[2][16 * 528];
    __shared__ __align__(16) float mslotW[2][16][16];  // per-wave rowmax slots, ring 2
    __shared__ float m0S[16];
    __shared__ float red[16][32];
    __shared__ int   lenS[16];
    __shared__ float mInitS;

    const int wv   = tid >> 6;          // 0..15
    const int lane = tid & 63;
    const int q    = lane >> 4;
    const int r15  = lane & 15;
    const int c5   = tid >> 5;          // init passes: threads 0..511
    const int s5   = tid & 31;

    if (is_fwd) {
        // ---- fwd init pass 1: m0 = max(emit[0]+tfs) per chain ----
        if (tid < 512) {
            float lmax = -3.0e38f;
#pragma unroll
            for (int i = 0; i < 4; ++i) {
                int j4 = s5 + 32 * i;
                float4v em = *(const float4v*)(emit + (size_t)(B0 + c5) * CC + 4 * j4);
                float4v tf = *(const float4v*)(tfs + 4 * j4);
                float4v a = em + tf;
                lmax = fmaxf(lmax, fmaxf(fmaxf(a.x, a.y), fmaxf(a.z, a.w)));
            }
            red[c5][s5] = lmax;
        }
        __syncthreads();
        if (tid < 16) {
            float m0 = red[tid][0];
            for (int s = 1; s < 32; ++s) m0 = fmaxf(m0, red[tid][s]);
            m0S[tid] = m0;
        }
        if (tid < 256) ((float*)&mslotW[0][0][0])[tid] = 1.0f;   // M'_0 = 1, all 16 wave slots
        __syncthreads();
        // ---- fwd init pass 2: store P0 (max = 1) in permuted layout ----
        if (tid < 512) {
            float m0 = m0S[c5];
#pragma unroll
            for (int i = 0; i < 4; ++i) {
                int pd = s5 + 32 * i;
                int wvv = pd >> 4, rw = pd & 15;
                float f[4];
#pragma unroll
                for (int nt = 0; nt < 4; ++nt) {
                    int k = 64 * wvv + 16 * nt + rw;
                    f[nt] = __expf(emit[(size_t)(B0 + c5) * CC + k] + tfs[k] - m0);
                }
                int r = 0;
                r = __builtin_amdgcn_cvt_pk_fp8_f32(f[0], f[1], r, false);
                r = __builtin_amdgcn_cvt_pk_fp8_f32(f[2], f[3], r, true);
                *(int*)(&p8[0][0] + c5 * 528 + pd * 4) = r;
            }
        }
        __syncthreads();
    } else {
        // ---- bwd init: mInit = max_k exp(t2e[k]) ----
        if (tid < 512) {
            float m = t2e[tid];
            for (int off = 32; off > 0; off >>= 1) m = fmaxf(m, __shfl_xor(m, off));
            if (lane == 0) ((float*)red)[wv] = m;
        }
        __syncthreads();
        if (tid == 0) {
            float m = ((float*)red)[0];
            for (int i = 1; i < 8; ++i) m = fmaxf(m, ((float*)red)[i]);
            mInitS = __expf(m);
        }
        __syncthreads();
        // ---- bwd init: beta_511 = exp(t2e) in BOTH buffers; chain lengths ----
        if (tid < 512) {
#pragma unroll
            for (int i = 0; i < 4; ++i) {
                int pd = s5 + 32 * i;
                int wvv = pd >> 4, rw = pd & 15;
                float f[4];
#pragma unroll
                for (int nt = 0; nt < 4; ++nt)
                    f[nt] = __expf(t2e[64 * wvv + 16 * nt + rw]);
                int r = 0;
                r = __builtin_amdgcn_cvt_pk_fp8_f32(f[0], f[1], r, false);
                r = __builtin_amdgcn_cvt_pk_fp8_f32(f[2], f[3], r, true);
                *(int*)(&p8[0][0] + c5 * 528 + pd * 4) = r;
                *(int*)(&p8[1][0] + c5 * 528 + pd * 4) = r;
            }
            int part = 0;
            for (int k = 0; k < 16; ++k)
                part += mask_at(maskp, is_byte, s5 * 16 + k, B0 + c5) ? 1 : 0;
            red[c5][s5] = (float)part;
        }
        __syncthreads();
        if (tid < 16) {
            int s = 0;
            for (int i = 0; i < 32; ++i) s += (int)red[tid][i];
            lenS[tid] = s;
        }
        __syncthreads();
    }

    // E column bases for this wave (L2-hot, re-read each step; NOT register-resident)
    const unsigned char* ews = ws + (is_fwd ? 0 : WS_ET);
    const unsigned char* pA = ews + (size_t)(wv * 32 + r15) * 512 + q * 32;
    const unsigned char* pB = pA + 16 * 512;
    const int wcol = (wv >> 1) * 64 + r15 * 4 + (wv & 1) * 2;

    int4v gsum = {0, 0, 0, 0};
    const float4v z4 = {0.f, 0.f, 0.f, 0.f};

    if (is_fwd) {
        // =========================== FORWARD: t = 1..255 ===========================
        const float* eb0 = emit + (size_t)(BB + B0 + q * 4) * CC + (wv * 32 + r15);
        const float* eb1 = eb0 + 2 * CC;
        float exv[8];
        exv[0] = __expf(eb0[0]);  exv[1] = __expf(eb0[CC]);
        exv[2] = __expf(eb1[0]);  exv[3] = __expf(eb1[CC]);
        exv[4] = __expf(eb0[16]); exv[5] = __expf(eb0[CC + 16]);
        exv[6] = __expf(eb1[16]); exv[7] = __expf(eb1[CC + 16]);

#pragma unroll 1
        for (int t = 1; t <= TM; ++t) {
            const int wp = t & 1, rp = wp ^ 1;
            eb0 += BB * CC;   // t+1 (t=TM reads t=256: valid, unused)
            eb1 += BB * CC;

            const unsigned char* pr = &p8[rp][0] + r15 * 528 + q * 32;

            // mslot reduce over 16 wave slots (u32 max == f32 max for positives)
            const char* mb = (const char*)&mslotW[(t - 1) & 1][0][q * 4];
            uint4v mm = *(const uint4v*)(mb);
#pragma unroll
            for (int i = 1; i < 16; ++i)
                mm = __builtin_elementwise_max(mm, *(const uint4v*)(mb + i * 64));

            // emission prefetch for t+1
            float emn[8];
            emn[0] = eb0[0];  emn[1] = eb0[CC];
            emn[2] = eb1[0];  emn[3] = eb1[CC];
            emn[4] = eb0[16]; emn[5] = eb0[CC + 16];
            emn[6] = eb1[16]; emn[7] = eb1[CC + 16];

            int4v e4 = {(int)(mm[0] >> 23), (int)(mm[1] >> 23), (int)(mm[2] >> 23), (int)(mm[3] >> 23)};
            int4v s2b = (248 - e4) << 23;
            float4v s24;
            s24[0] = __int_as_float(s2b[0]); s24[1] = __int_as_float(s2b[1]);
            s24[2] = __int_as_float(s2b[2]); s24[3] = __int_as_float(s2b[3]);

            float4v acc0 = z4, acc1 = z4;
            // staged MFMA: ping-pong loads one kk4 ahead (af from LDS, eA/eB from L2)
            int4v afl[2], afh[2], eal[2], eah[2], ebl[2], ebh[2];
            afl[0] = *(const int4v*)(pr);       afh[0] = *(const int4v*)(pr + 16);
            eal[0] = *(const int4v*)(pA);       eah[0] = *(const int4v*)(pA + 16);
            ebl[0] = *(const int4v*)(pB);       ebh[0] = *(const int4v*)(pB + 16);
#pragma unroll
            for (int k = 0; k < 4; ++k) {
                const int cur = k & 1, nxt = cur ^ 1;
                if (k < 3) {
                    afl[nxt] = *(const int4v*)(pr + (k + 1) * 128);
                    afh[nxt] = *(const int4v*)(pr + (k + 1) * 128 + 16);
                    eal[nxt] = *(const int4v*)(pA + (k + 1) * 128);
                    eah[nxt] = *(const int4v*)(pA + (k + 1) * 128 + 16);
                    ebl[nxt] = *(const int4v*)(pB + (k + 1) * 128);
                    ebh[nxt] = *(const int4v*)(pB + (k + 1) * 128 + 16);
                }
                int8v af = __builtin_shufflevector(afl[cur], afh[cur], 0, 1, 2, 3, 4, 5, 6, 7);
                int8v eA = __builtin_shufflevector(eal[cur], eah[cur], 0, 1, 2, 3, 4, 5, 6, 7);
                int8v eB = __builtin_shufflevector(ebl[cur], ebh[cur], 0, 1, 2, 3, 4, 5, 6, 7);
                acc0 = __builtin_amdgcn_mfma_scale_f32_16x16x128_f8f6f4(
                    af, eA, acc0, 0, 0, 0, 0x7F7F7F7F, 0, 0x7F7F7F7F);
                acc1 = __builtin_amdgcn_mfma_scale_f32_16x16x128_f8f6f4(
                    af, eB, acc1, 0, 0, 0, 0x7F7F7F7F, 0, 0x7F7F7F7F);
            }

            // epilogue
            float4v p0, p1;
#pragma unroll
            for (int rr = 0; rr < 4; ++rr) {
                p0[rr] = acc0[rr] * (exv[rr] * s24[rr]);
                p1[rr] = acc1[rr] * (exv[4 + rr] * s24[rr]);
            }

            if (t == TM) {   // export stored-scale alpha_255 (f32, class order)
                float* wA = (float*)(ws + WS_ALPHA) + (size_t)(B0 + q * 4) * CC + (wv * 32 + r15);
#pragma unroll
                for (int rr = 0; rr < 4; ++rr) {
                    wA[(size_t)rr * CC + 0]  = p0[rr];
                    wA[(size_t)rr * CC + 16] = p1[rr];
                }
            }

            {
                float4v rm4 = __builtin_elementwise_max(p0, p1);
                float4v rw;
#pragma unroll
                for (int rr = 0; rr < 4; ++rr) rw[rr] = rowmax16_dpp(rm4[rr]);
                if (r15 == 0)
                    *(float4v*)&mslotW[t & 1][wv][q * 4] = rw;
            }

            {
                unsigned char* wrow = &p8[wp][0] + wcol;
#pragma unroll
                for (int rr = 0; rr < 4; ++rr) {
                    int r = __builtin_amdgcn_cvt_pk_fp8_f32(
                        fminf(p0[rr], 448.0f), fminf(p1[rr], 448.0f), 0, false);
                    *(short*)(wrow + (q * 4 + rr) * 528) = (short)r;
                }
            }

            gsum += (e4 - 121);   // uniform per lane-group

#pragma unroll
            for (int i = 0; i < 8; ++i) exv[i] = __expf(emn[i]);
            step_barrier();
        }
        if (wv == 0 && r15 == 0) {
#pragma unroll
            for (int rr = 0; rr < 4; ++rr)
                ((float*)(ws + WS_SVA))[B0 + q * 4 + rr] =
                    m0S[q * 4 + rr] + 0.6931471805599453f * (float)gsum[rr];
        }
    } else {
        // =========================== BACKWARD: t = 510..255 ===========================
        int lenR[4];
#pragma unroll
        for (int rr = 0; rr < 4; ++rr) lenR[rr] = lenS[q * 4 + rr];
        const int eInit = __float_as_int(mInitS) >> 23;
        const float e2a = __expf(t2e[wv * 32 + r15]);
        const float e2b = __expf(t2e[wv * 32 + 16 + r15]);

        const float* eb0 = emit + ((size_t)(LL - 1) * BB + B0 + q * 4) * CC + (wv * 32 + r15);
        const float* eb1 = eb0 + 2 * CC;
        float exv[8];
        exv[0] = __expf(eb0[0]);  exv[1] = __expf(eb0[CC]);
        exv[2] = __expf(eb1[0]);  exv[3] = __expf(eb1[CC]);
        exv[4] = __expf(eb0[16]); exv[5] = __expf(eb0[CC + 16]);
        exv[6] = __expf(eb1[16]); exv[7] = __expf(eb1[CC + 16]);

#pragma unroll 1
        for (int it = 0; it < 256; ++it) {
            const int t  = 510 - it;
            const int wp = it & 1, rp = wp ^ 1;
            eb0 -= BB * CC;   // it=255 region valid, unused
            eb1 -= BB * CC;

            const unsigned char* pr = &p8[rp][0] + r15 * 528 + q * 32;

            const char* mb = (const char*)&mslotW[(it - 1) & 1][0][q * 4];
            uint4v mm = *(const uint4v*)(mb);
#pragma unroll
            for (int i = 1; i < 16; ++i)
                mm = __builtin_elementwise_max(mm, *(const uint4v*)(mb + i * 64));

            float emn[8];
            emn[0] = eb0[0];  emn[1] = eb0[CC];
            emn[2] = eb1[0];  emn[3] = eb1[CC];
            emn[4] = eb0[16]; emn[5] = eb0[CC + 16];
            emn[6] = eb1[16]; emn[7] = eb1[CC + 16];

            // per-row g select: frozen-prev rows (t >= len-2) use eInit
            int4v e4 = {(int)(mm[0] >> 23), (int)(mm[1] >> 23), (int)(mm[2] >> 23), (int)(mm[3] >> 23)};
            int4v eU;
            float4v s2U;
            bool lv[4];
#pragma unroll
            for (int rr = 0; rr < 4; ++rr) {
                bool ui = (t >= lenR[rr] - 2);
                lv[rr] = (t <= lenR[rr] - 2);
                int e = ui ? eInit : e4[rr];
                eU[rr] = e;
                s2U[rr] = __int_as_float((248 - e) << 23);
            }

            float4v acc0 = z4, acc1 = z4;
            int4v afl[2], afh[2], eal[2], eah[2], ebl[2], ebh[2];
            afl[0] = *(const int4v*)(pr);       afh[0] = *(const int4v*)(pr + 16);
            eal[0] = *(const int4v*)(pA);       eah[0] = *(const int4v*)(pA + 16);
            ebl[0] = *(const int4v*)(pB);       ebh[0] = *(const int4v*)(pB + 16);
#pragma unroll
            for (int k = 0; k < 4; ++k) {
                const int cur = k & 1, nxt = cur ^ 1;
                if (k < 3) {
                    afl[nxt] = *(const int4v*)(pr + (k + 1) * 128);
                    afh[nxt] = *(const int4v*)(pr + (k + 1) * 128 + 16);
                    eal[nxt] = *(const int4v*)(pA + (k + 1) * 128);
                    eah[nxt] = *(const int4v*)(pA + (k + 1) * 128 + 16);
                    ebl[nxt] = *(const int4v*)(pB + (k + 1) * 128);
                    ebh[nxt] = *(const int4v*)(pB + (k + 1) * 128 + 16);
                }
                int8v af = __builtin_shufflevector(afl[cur], afh[cur], 0, 1, 2, 3, 4, 5, 6, 7);
                int8v eA = __builtin_shufflevector(eal[cur], eah[cur], 0, 1, 2, 3, 4, 5, 6, 7);
                int8v eB = __builtin_shufflevector(ebl[cur], ebh[cur], 0, 1, 2, 3, 4, 5, 6, 7);
                acc0 = __builtin_amdgcn_mfma_scale_f32_16x16x128_f8f6f4(
                    af, eA, acc0, 0, 0, 0, 0x7F7F7F7F, 0, 0x7F7F7F7F);
                acc1 = __builtin_amdgcn_mfma_scale_f32_16x16x128_f8f6f4(
                    af, eB, acc1, 0, 0, 0, 0x7F7F7F7F, 0, 0x7F7F7F7F);
            }

            float4v p0, p1;
#pragma unroll
            for (int rr = 0; rr < 4; ++rr) {
                p0[rr] = acc0[rr] * (exv[rr] * s2U[rr]);
                p1[rr] = acc1[rr] * (exv[4 + rr] * s2U[rr]);
            }

            if (t == TM) {   // export stored-scale beta_255 (frozen chains: e^{t2e})
                float* wB = (float*)(ws + WS_BETA) + (size_t)(B0 + q * 4) * CC + (wv * 32 + r15);
#pragma unroll
                for (int rr = 0; rr < 4; ++rr) {
                    wB[(size_t)rr * CC + 0]  = lv[rr] ? p0[rr] : e2a;
                    wB[(size_t)rr * CC + 16] = lv[rr] ? p1[rr] : e2b;
                }
            }

            {
                float4v rm4 = __builtin_elementwise_max(p0, p1);
                float4v rw;
#pragma unroll
                for (int rr = 0; rr < 4; ++rr) rw[rr] = rowmax16_dpp(rm4[rr]);
                if (r15 == 0)
                    *(float4v*)&mslotW[it & 1][wv][q * 4] = rw;
            }

            {
                unsigned char* wrow = &p8[wp][0] + wcol;
#pragma unroll
                for (int rr = 0; rr < 4; ++rr) {
                    int r = __builtin_amdgcn_cvt_pk_fp8_f32(
                        fminf(p0[rr], 448.0f), fminf(p1[rr], 448.0f), 0, false);
                    if (lv[rr])   // live update only; frozen rows keep init
                        *(short*)(wrow + (q * 4 + rr) * 528) = (short)r;
                }
            }

#pragma unroll
            for (int rr = 0; rr < 4; ++rr)
                gsum[rr] += lv[rr] ? (eU[rr] - 121) : 0;

#pragma unroll
            for (int i = 0; i < 8; ++i) exv[i] = __expf(emn[i]);
            step_barrier();
        }
        if (wv == 0 && r15 == 0) {
#pragma unroll
            for (int rr = 0; rr < 4; ++rr)
                ((float*)(ws + WS_SVB))[B0 + q * 4 + rr] =
                    0.6931471805599453f * (float)gsum[rr];
        }
    }
}

// ---------------- combine: logZ_b = SvA_b + SvB_b + log(alpha_255 . beta_255) -----------
__global__ void combine_kernel(const unsigned char* __restrict__ ws, float* __restrict__ out) {
    __shared__ float acc8[8];
    const int tid = threadIdx.x;
    const int c  = tid >> 3;
    const int s8 = tid & 7;
    const float* A = (const float*)(ws + WS_ALPHA) + (size_t)c * CC;
    const float* B = (const float*)(ws + WS_BETA)  + (size_t)c * CC;
    float d = 0.0f;
    for (int i = s8; i < CC; i += 8) d += A[i] * B[i];
    d += __shfl_xor(d, 1);
    d += __shfl_xor(d, 2);
    d += __shfl_xor(d, 4);
    float v = 0.0f;
    if (s8 == 0)
        v = ((const float*)(ws + WS_SVA))[c] + ((const float*)(ws + WS_SVB))[c] + __logf(d);
    for (int off = 32; off > 0; off >>= 1) v += __shfl_down(v, off);
    if ((tid & 63) == 0) acc8[tid >> 6] = v;
    __syncthreads();
    if (tid == 0) {
        float s = 0.0f;
        for (int i = 0; i < 8; ++i) s += acc8[i];
        out[0] = (s - *(const float*)(ws + WS_SCORE)) * (1.0f / 64.0f);
    }
}

extern "C" void kernel_launch(void* const* d_in, const int* in_sizes, int n_in,
                              void* d_out, int out_size, void* d_ws, size_t ws_size,
                              hipStream_t stream) {
    const float* emit   = (const float*)d_in[0];
    const int*   target = (const int*)d_in[1];
    const void*  maskp  = d_in[2];
    const float* trans  = (const float*)d_in[3];
    const float* tfs    = (const float*)d_in[4];
    const float* t2e    = (const float*)d_in[5];
    unsigned char* ws   = (unsigned char*)d_ws;
    float* out          = (float*)d_out;

    prep_kernel<<<256, 256, 0, stream>>>(trans, ws);
    crf_scan_kernel<<<40, 1024, 0, stream>>>(emit, target, maskp, trans, tfs, t2e, ws);
    combine_kernel<<<1, 512, 0, stream>>>(ws, out);
}

// Round 10
// 493.388 us; speedup vs baseline: 4.1783x; 4.1783x over previous
//
#include <hip/hip_runtime.h>
#include <hip/hip_bf16.h>
#include <stdint.h>

#define LL 512
#define BB 64
#define CC 512
#define TM 255   // meeting point: fwd covers emits 0..255, bwd covers 256..511

typedef float float4v __attribute__((ext_vector_type(4)));
typedef int   int4v   __attribute__((ext_vector_type(4)));
typedef unsigned int uint4v __attribute__((ext_vector_type(4)));
typedef int   int8v  __attribute__((ext_vector_type(8)));

// ws layout (bytes)
#define WS_ET     262144   // E^T fp8 (E fwd fp8 at 0)
#define WS_SCORE  524288   // f32
#define WS_SVA    524292   // 64 f32
#define WS_SVB    524548   // 64 f32
#define WS_ALPHA  528384   // 64*512 f32 (class-ordered)
#define WS_BETA   659456   // 64*512 f32 (class-ordered)

// position permutation shared by p8 rows and E/E^T columns:
//   kperm(P) = 64*(P>>6) + 16*(P&3) + ((P>>2)&15)
//
// normalization (pow2): stored S_t = quant(v_t * 2^-g_t), v_t = MFMA(S_{t-1})*ex_t,
//   g_t = floor(log2(M'_{t-1})) + 6,  M'_{t-1} = max(stored S_{t-1})
//   M' tracking is ATOMIC-FREE: each wave writes its 16 row-maxes to
//   mslotW[t&1][wv][chain]; the consumer (next step) u32-maxes the 8 wave slots.
//   true alpha_t = S_t * D_t, logD = gsum * ln2  (exact)

__device__ __forceinline__ bool mask_at(const void* maskp, bool is_byte, int t, int b) {
    if (is_byte) return ((const unsigned char*)maskp)[t * BB + b] != 0;
    return ((const int*)maskp)[t * BB + b] != 0;
}

__device__ __forceinline__ float rowmax16_dpp(float x) {
    int t;
    t = __builtin_amdgcn_update_dpp(0, __float_as_int(x), 0x128, 0xF, 0xF, true); // ror:8
    x = fmaxf(x, __int_as_float(t));
    t = __builtin_amdgcn_update_dpp(0, __float_as_int(x), 0x124, 0xF, 0xF, true); // ror:4
    x = fmaxf(x, __int_as_float(t));
    t = __builtin_amdgcn_update_dpp(0, __float_as_int(x), 0x122, 0xF, 0xF, true); // ror:2
    x = fmaxf(x, __int_as_float(t));
    t = __builtin_amdgcn_update_dpp(0, __float_as_int(x), 0x121, 0xF, 0xF, true); // ror:1
    x = fmaxf(x, __int_as_float(t));
    return x;
}

// LDS-exchange barrier WITHOUT vmcnt drain: global prefetches stay in flight.
__device__ __forceinline__ void step_barrier() {
    asm volatile("s_waitcnt lgkmcnt(0)" ::: "memory");
    __builtin_amdgcn_sched_barrier(0);
    __builtin_amdgcn_s_barrier();
    asm volatile("" ::: "memory");
}

// E (fwd) and E^T (bwd) in fp8, permuted layout. Also zero the score slot.
__global__ void prep_kernel(const float* __restrict__ trans, unsigned char* __restrict__ ws) {
    int g = blockIdx.x * blockDim.x + threadIdx.x;
    if (g == 0) *(float*)(ws + WS_SCORE) = 0.0f;
    if (g >= 512 * 128) return;
    int n  = g & 511;
    int pd = g >> 9;
    int wv = pd >> 4, rw = pd & 15;
    float f[4], ft[4];
#pragma unroll
    for (int nt = 0; nt < 4; ++nt) {
        int k = 64 * wv + 16 * nt + rw;
        f[nt]  = __expf(trans[(size_t)k * CC + n]);   // E[k][n]
        ft[nt] = __expf(trans[(size_t)n * CC + k]);   // E[n][k]
    }
    int r = 0;
    r = __builtin_amdgcn_cvt_pk_fp8_f32(f[0], f[1], r, false);
    r = __builtin_amdgcn_cvt_pk_fp8_f32(f[2], f[3], r, true);
    ((int*)ws)[n * 128 + pd] = r;
    int r2 = 0;
    r2 = __builtin_amdgcn_cvt_pk_fp8_f32(ft[0], ft[1], r2, false);
    r2 = __builtin_amdgcn_cvt_pk_fp8_f32(ft[2], ft[3], r2, true);
    ((int*)(ws + WS_ET))[n * 128 + pd] = r2;
}

// blocks 0..3: fwd alpha t=1..255 (len>=256 -> unguarded)
// blocks 4..7: bwd beta t=510..255 (freeze-until-birth)
// blocks 8..39: score
__launch_bounds__(512, 2)
__global__ void crf_scan_kernel(const float* __restrict__ emit,
                                const int* __restrict__ target,
                                const void* __restrict__ maskp,
                                const float* __restrict__ trans,
                                const float* __restrict__ tfs,
                                const float* __restrict__ t2e,
                                unsigned char* __restrict__ ws) {
    const int tid = threadIdx.x;
    const bool is_byte = ((const unsigned char*)maskp)[1] != 0;

    if (blockIdx.x >= 8) {   // -------- score part --------
        int sb = blockIdx.x - 8;
        float val = 0.0f;
        for (int e = sb * 512 + tid; e < LL * BB; e += 32 * 512) {
            int t = e >> 6, b = e & 63;
            if (mask_at(maskp, is_byte, t, b)) {
                int tg  = target[t * BB + b];
                float v = emit[(size_t)(t * BB + b) * CC + tg];
                if (t > 0) v += trans[(size_t)target[(t - 1) * BB + b] * CC + tg];
                val += v;
            }
        }
        if (sb == 0 && tid < BB) {
            int b = tid;
            val += tfs[target[b]];
            int lo = 0, hi = LL;
            while (lo < hi) {
                int mid = (lo + hi) >> 1;
                if (mask_at(maskp, is_byte, mid, b)) lo = mid + 1; else hi = mid;
            }
            val += t2e[target[(lo - 1) * BB + b]];
        }
        for (int off = 32; off > 0; off >>= 1) val += __shfl_down(val, off);
        if ((tid & 63) == 0) atomicAdd((float*)(ws + WS_SCORE), val);
        return;
    }

    const bool is_fwd = blockIdx.x < 4;
    const int B0 = (is_fwd ? blockIdx.x : blockIdx.x - 4) * 16;

    __shared__ __align__(16) unsigned char p8[2][16 * 528];
    __shared__ __align__(16) float mslotW[2][8][16];   // per-wave rowmax slots, ring 2
    __shared__ float m0S[16];
    __shared__ float red[16][32];
    __shared__ int   lenS[16];
    __shared__ float mInitS;

    const int wv   = tid >> 6;
    const int lane = tid & 63;
    const int q    = lane >> 4;
    const int r15  = lane & 15;

    // E (B operand) fragments resident in VGPRs (AGPR-backed)
    const unsigned char* ews = ws + (is_fwd ? 0 : WS_ET);
    int8v ef[4][4];
#pragma unroll
    for (int nt = 0; nt < 4; ++nt) {
        int n = (wv * 4 + nt) * 16 + r15;
#pragma unroll
        for (int kk4 = 0; kk4 < 4; ++kk4) {
            const unsigned char* src = ews + n * 512 + kk4 * 128 + q * 32;
            int4v lo = *(const int4v*)(src);
            int4v hi = *(const int4v*)(src + 16);
            ef[nt][kk4] = __builtin_shufflevector(lo, hi, 0, 1, 2, 3, 4, 5, 6, 7);
        }
    }

    const int c5 = tid >> 5;
    const int s5 = tid & 31;

    if (is_fwd) {
        // ---- fwd init pass 1: m0 = max(emit[0]+tfs) per chain ----
        {
            float lmax = -3.0e38f;
#pragma unroll
            for (int i = 0; i < 4; ++i) {
                int j4 = s5 + 32 * i;
                float4v em = *(const float4v*)(emit + (size_t)(B0 + c5) * CC + 4 * j4);
                float4v tf = *(const float4v*)(tfs + 4 * j4);
                float4v a = em + tf;
                lmax = fmaxf(lmax, fmaxf(fmaxf(a.x, a.y), fmaxf(a.z, a.w)));
            }
            red[c5][s5] = lmax;
        }
        __syncthreads();
        if (tid < 16) {
            float m0 = red[tid][0];
            for (int s = 1; s < 32; ++s) m0 = fmaxf(m0, red[tid][s]);
            m0S[tid] = m0;
        }
        if (tid < 128) ((float*)&mslotW[0][0][0])[tid] = 1.0f;   // M'_0 = 1, all wave slots
        __syncthreads();
        // ---- fwd init pass 2: store P0 (max = 1) in permuted layout ----
        {
            float m0 = m0S[c5];
#pragma unroll
            for (int i = 0; i < 4; ++i) {
                int pd = s5 + 32 * i;
                int wvv = pd >> 4, rw = pd & 15;
                float f[4];
#pragma unroll
                for (int nt = 0; nt < 4; ++nt) {
                    int k = 64 * wvv + 16 * nt + rw;
                    f[nt] = __expf(emit[(size_t)(B0 + c5) * CC + k] + tfs[k] - m0);
                }
                int r = 0;
                r = __builtin_amdgcn_cvt_pk_fp8_f32(f[0], f[1], r, false);
                r = __builtin_amdgcn_cvt_pk_fp8_f32(f[2], f[3], r, true);
                *(int*)(&p8[0][0] + c5 * 528 + pd * 4) = r;
            }
        }
        __syncthreads();
    } else {
        // ---- bwd init: mInit = max_k exp(t2e[k]) ----
        {
            float m = t2e[tid];
            for (int off = 32; off > 0; off >>= 1) m = fmaxf(m, __shfl_xor(m, off));
            if (lane == 0) ((float*)red)[wv] = m;
        }
        __syncthreads();
        if (tid == 0) {
            float m = ((float*)red)[0];
            for (int i = 1; i < 8; ++i) m = fmaxf(m, ((float*)red)[i]);
            mInitS = __expf(m);
        }
        __syncthreads();
        // ---- bwd init: beta_511 = exp(t2e) in BOTH buffers; chain lengths ----
        {
#pragma unroll
            for (int i = 0; i < 4; ++i) {
                int pd = s5 + 32 * i;
                int wvv = pd >> 4, rw = pd & 15;
                float f[4];
#pragma unroll
                for (int nt = 0; nt < 4; ++nt)
                    f[nt] = __expf(t2e[64 * wvv + 16 * nt + rw]);
                int r = 0;
                r = __builtin_amdgcn_cvt_pk_fp8_f32(f[0], f[1], r, false);
                r = __builtin_amdgcn_cvt_pk_fp8_f32(f[2], f[3], r, true);
                *(int*)(&p8[0][0] + c5 * 528 + pd * 4) = r;
                *(int*)(&p8[1][0] + c5 * 528 + pd * 4) = r;
            }
            int part = 0;
            for (int k = 0; k < 16; ++k)
                part += mask_at(maskp, is_byte, s5 * 16 + k, B0 + c5) ? 1 : 0;
            red[c5][s5] = (float)part;
        }
        __syncthreads();
        if (tid < 16) {
            int s = 0;
            for (int i = 0; i < 32; ++i) s += (int)red[tid][i];
            lenS[tid] = s;
        }
        __syncthreads();
    }

    int4v gsum = {0, 0, 0, 0};
    const float4v z4 = {0.f, 0.f, 0.f, 0.f};

    if (is_fwd) {
        // =========================== FORWARD: t = 1..255 ===========================
        const float* eb0 = emit + (size_t)(BB + B0 + q * 4) * CC + (wv * 64 + r15);
        const float* eb1 = eb0 + 2 * CC;
        float4v ex4[4];
#pragma unroll
        for (int nt = 0; nt < 4; ++nt) {
            ex4[nt][0] = __expf(eb0[0 * CC + nt * 16]);
            ex4[nt][1] = __expf(eb0[1 * CC + nt * 16]);
            ex4[nt][2] = __expf(eb1[0 * CC + nt * 16]);
            ex4[nt][3] = __expf(eb1[1 * CC + nt * 16]);
        }

#pragma unroll 2
        for (int t = 1; t <= TM; ++t) {
            const int wp = t & 1;
            const int rp = wp ^ 1;
            eb0 += BB * CC;   // now points at t+1 (t=TM reads t=256: valid, unused)
            eb1 += BB * CC;

            const unsigned char* pr = &p8[rp][0] + r15 * 528 + q * 32;
            int8v af[4];
#pragma unroll
            for (int kk4 = 0; kk4 < 4; ++kk4) {
                int4v lo = *(const int4v*)(pr + kk4 * 128);
                int4v hi = *(const int4v*)(pr + kk4 * 128 + 16);
                af[kk4] = __builtin_shufflevector(lo, hi, 0, 1, 2, 3, 4, 5, 6, 7);
            }

            // consumer-side max over the 8 wave slots (u32 max == f32 max for positives)
            const char* mb = (const char*)&mslotW[(t - 1) & 1][0][q * 4];
            uint4v mm = *(const uint4v*)(mb);
#pragma unroll
            for (int i = 1; i < 8; ++i)
                mm = __builtin_elementwise_max(mm, *(const uint4v*)(mb + i * 64));

            float4v emn4[4];
#pragma unroll
            for (int nt = 0; nt < 4; ++nt) {
                emn4[nt][0] = eb0[0 * CC + nt * 16];
                emn4[nt][1] = eb0[1 * CC + nt * 16];
                emn4[nt][2] = eb1[0 * CC + nt * 16];
                emn4[nt][3] = eb1[1 * CC + nt * 16];
            }

            // s2 = 2^-(e-121), g = e-121  (sigma = 64*pow2floor(M'))
            int4v e4 = {(int)(mm[0] >> 23), (int)(mm[1] >> 23), (int)(mm[2] >> 23), (int)(mm[3] >> 23)};
            int4v s2b = (248 - e4) << 23;
            float4v s24;
            s24[0] = __int_as_float(s2b[0]); s24[1] = __int_as_float(s2b[1]);
            s24[2] = __int_as_float(s2b[2]); s24[3] = __int_as_float(s2b[3]);

            float4v acc[4];
#pragma unroll
            for (int nt = 0; nt < 4; ++nt) acc[nt] = z4;

#pragma unroll
            for (int kk4 = 0; kk4 < 4; ++kk4)
#pragma unroll
                for (int nt = 0; nt < 2; ++nt)
                    acc[nt] = __builtin_amdgcn_mfma_scale_f32_16x16x128_f8f6f4(
                        af[kk4], ef[nt][kk4], acc[nt],
                        0, 0, 0, 0x7F7F7F7F, 0, 0x7F7F7F7F);

            float4v exn4[4];
#pragma unroll
            for (int nt = 0; nt < 4; ++nt) {
                exn4[nt][0] = __expf(emn4[nt][0]);
                exn4[nt][1] = __expf(emn4[nt][1]);
                exn4[nt][2] = __expf(emn4[nt][2]);
                exn4[nt][3] = __expf(emn4[nt][3]);
            }

#pragma unroll
            for (int kk4 = 0; kk4 < 4; ++kk4)
#pragma unroll
                for (int nt = 2; nt < 4; ++nt)
                    acc[nt] = __builtin_amdgcn_mfma_scale_f32_16x16x128_f8f6f4(
                        af[kk4], ef[nt][kk4], acc[nt],
                        0, 0, 0, 0x7F7F7F7F, 0, 0x7F7F7F7F);

            // p = acc * (ex * 2^-g)   (stored-scale output)
            float4v p4[4];
#pragma unroll
            for (int nt = 0; nt < 4; ++nt) {
                float4v exr = ex4[nt] * s24;
                p4[nt] = acc[nt] * exr;
            }

            if (t == TM) {   // export stored-scale alpha_255 (f32, class order)
                float* wA = (float*)(ws + WS_ALPHA) + (size_t)(B0 + q * 4) * CC + (wv * 64 + r15);
#pragma unroll
                for (int nt = 0; nt < 4; ++nt)
#pragma unroll
                    for (int rr = 0; rr < 4; ++rr)
                        wA[(size_t)rr * CC + nt * 16] = p4[nt][rr];
            }

            // rowmax (stored scale) -> DPP -> plain per-wave slot write (no atomics)
            {
                float4v rm4 = __builtin_elementwise_max(
                    __builtin_elementwise_max(p4[0], p4[1]),
                    __builtin_elementwise_max(p4[2], p4[3]));
                float4v rw;
#pragma unroll
                for (int rr = 0; rr < 4; ++rr) rw[rr] = rowmax16_dpp(rm4[rr]);
                if (r15 == 0)
                    *(float4v*)&mslotW[t & 1][wv][q * 4] = rw;
            }

            // quantize + store
            {
                unsigned char* wrow = &p8[wp][0] + (wv * 16 + r15) * 4;
#pragma unroll
                for (int rr = 0; rr < 4; ++rr) {
                    float p0 = fminf(p4[0][rr], 448.0f);
                    float p1 = fminf(p4[1][rr], 448.0f);
                    float p2 = fminf(p4[2][rr], 448.0f);
                    float p3 = fminf(p4[3][rr], 448.0f);
                    int r = 0;
                    r = __builtin_amdgcn_cvt_pk_fp8_f32(p0, p1, r, false);
                    r = __builtin_amdgcn_cvt_pk_fp8_f32(p2, p3, r, true);
                    *(int*)(wrow + (q * 4 + rr) * 528) = r;
                }
            }

            if (wv == 0 && r15 == 0) gsum += (e4 - 121);   // fwd: always live

#pragma unroll
            for (int nt = 0; nt < 4; ++nt) ex4[nt] = exn4[nt];
            step_barrier();
        }
        if (wv == 0 && r15 == 0) {
#pragma unroll
            for (int rr = 0; rr < 4; ++rr)
                ((float*)(ws + WS_SVA))[B0 + q * 4 + rr] =
                    m0S[q * 4 + rr] + 0.6931471805599453f * (float)gsum[rr];
        }
    } else {
        // =========================== BACKWARD: t = 510..255 ===========================
        int lenR[4];
#pragma unroll
        for (int rr = 0; rr < 4; ++rr) lenR[rr] = lenS[q * 4 + rr];
        const int eInit = __float_as_int(mInitS) >> 23;

        const float* eb0 = emit + ((size_t)(LL - 1) * BB + B0 + q * 4) * CC + (wv * 64 + r15);
        const float* eb1 = eb0 + 2 * CC;
        float4v ex4[4];
#pragma unroll
        for (int nt = 0; nt < 4; ++nt) {
            ex4[nt][0] = __expf(eb0[0 * CC + nt * 16]);
            ex4[nt][1] = __expf(eb0[1 * CC + nt * 16]);
            ex4[nt][2] = __expf(eb1[0 * CC + nt * 16]);
            ex4[nt][3] = __expf(eb1[1 * CC + nt * 16]);
        }

#pragma unroll 2
        for (int it = 0; it < 256; ++it) {
            const int t  = 510 - it;
            const int wp = it & 1;
            const int rp = wp ^ 1;
            eb0 -= BB * CC;   // it=255 region valid, unused
            eb1 -= BB * CC;

            const unsigned char* pr = &p8[rp][0] + r15 * 528 + q * 32;
            int8v af[4];
#pragma unroll
            for (int kk4 = 0; kk4 < 4; ++kk4) {
                int4v lo = *(const int4v*)(pr + kk4 * 128);
                int4v hi = *(const int4v*)(pr + kk4 * 128 + 16);
                af[kk4] = __builtin_shufflevector(lo, hi, 0, 1, 2, 3, 4, 5, 6, 7);
            }

            const char* mb = (const char*)&mslotW[(it - 1) & 1][0][q * 4];
            uint4v mm = *(const uint4v*)(mb);
#pragma unroll
            for (int i = 1; i < 8; ++i)
                mm = __builtin_elementwise_max(mm, *(const uint4v*)(mb + i * 64));

            float4v emn4[4];
#pragma unroll
            for (int nt = 0; nt < 4; ++nt) {
                emn4[nt][0] = eb0[0 * CC + nt * 16];
                emn4[nt][1] = eb0[1 * CC + nt * 16];
                emn4[nt][2] = eb1[0 * CC + nt * 16];
                emn4[nt][3] = eb1[1 * CC + nt * 16];
            }

            // per-row g select: frozen-prev rows (t >= len-2) use eInit (prev = init, scale 1)
            int4v e4 = {(int)(mm[0] >> 23), (int)(mm[1] >> 23), (int)(mm[2] >> 23), (int)(mm[3] >> 23)};
            int4v eU;
            float4v s2U;
#pragma unroll
            for (int rr = 0; rr < 4; ++rr) {
                bool ui = (t >= lenR[rr] - 2);
                int e = ui ? eInit : e4[rr];
                eU[rr] = e;
                s2U[rr] = __int_as_float((248 - e) << 23);
            }

            float4v acc[4];
#pragma unroll
            for (int nt = 0; nt < 4; ++nt) acc[nt] = z4;

#pragma unroll
            for (int kk4 = 0; kk4 < 4; ++kk4)
#pragma unroll
                for (int nt = 0; nt < 2; ++nt)
                    acc[nt] = __builtin_amdgcn_mfma_scale_f32_16x16x128_f8f6f4(
                        af[kk4], ef[nt][kk4], acc[nt],
                        0, 0, 0, 0x7F7F7F7F, 0, 0x7F7F7F7F);

            float4v exn4[4];
#pragma unroll
            for (int nt = 0; nt < 4; ++nt) {
                exn4[nt][0] = __expf(emn4[nt][0]);
                exn4[nt][1] = __expf(emn4[nt][1]);
                exn4[nt][2] = __expf(emn4[nt][2]);
                exn4[nt][3] = __expf(emn4[nt][3]);
            }

#pragma unroll
            for (int kk4 = 0; kk4 < 4; ++kk4)
#pragma unroll
                for (int nt = 2; nt < 4; ++nt)
                    acc[nt] = __builtin_amdgcn_mfma_scale_f32_16x16x128_f8f6f4(
                        af[kk4], ef[nt][kk4], acc[nt],
                        0, 0, 0, 0x7F7F7F7F, 0, 0x7F7F7F7F);

            float4v p4[4];
#pragma unroll
            for (int nt = 0; nt < 4; ++nt) {
                float4v exr = ex4[nt] * s2U;
                p4[nt] = acc[nt] * exr;
            }

            if (t == TM) {   // export stored-scale beta_255 (frozen chains: e^{t2e} row)
                float* wB = (float*)(ws + WS_BETA) + (size_t)(B0 + q * 4) * CC + (wv * 64 + r15);
#pragma unroll
                for (int nt = 0; nt < 4; ++nt) {
                    float e2 = __expf(t2e[wv * 64 + nt * 16 + r15]);
#pragma unroll
                    for (int rr = 0; rr < 4; ++rr)
                        wB[(size_t)rr * CC + nt * 16] = (t <= lenR[rr] - 2) ? p4[nt][rr] : e2;
                }
            }

            {
                float4v rm4 = __builtin_elementwise_max(
                    __builtin_elementwise_max(p4[0], p4[1]),
                    __builtin_elementwise_max(p4[2], p4[3]));
                float4v rw;
#pragma unroll
                for (int rr = 0; rr < 4; ++rr) rw[rr] = rowmax16_dpp(rm4[rr]);
                if (r15 == 0)
                    *(float4v*)&mslotW[it & 1][wv][q * 4] = rw;
            }

            {
                unsigned char* wrow = &p8[wp][0] + (wv * 16 + r15) * 4;
#pragma unroll
                for (int rr = 0; rr < 4; ++rr) {
                    float p0 = fminf(p4[0][rr], 448.0f);
                    float p1 = fminf(p4[1][rr], 448.0f);
                    float p2 = fminf(p4[2][rr], 448.0f);
                    float p3 = fminf(p4[3][rr], 448.0f);
                    int r = 0;
                    r = __builtin_amdgcn_cvt_pk_fp8_f32(p0, p1, r, false);
                    r = __builtin_amdgcn_cvt_pk_fp8_f32(p2, p3, r, true);
                    if (t <= lenR[rr] - 2)   // live update only; frozen rows keep init
                        *(int*)(wrow + (q * 4 + rr) * 528) = r;
                }
            }

            if (wv == 0 && r15 == 0) {
#pragma unroll
                for (int rr = 0; rr < 4; ++rr)
                    if (t <= lenR[rr] - 2) gsum[rr] += (eU[rr] - 121);
            }

#pragma unroll
            for (int nt = 0; nt < 4; ++nt) ex4[nt] = exn4[nt];
            step_barrier();
        }
        if (wv == 0 && r15 == 0) {
#pragma unroll
            for (int rr = 0; rr < 4; ++rr)
                ((float*)(ws + WS_SVB))[B0 + q * 4 + rr] =
                    0.6931471805599453f * (float)gsum[rr];
        }
    }
}

// ---------------- combine: logZ_b = SvA_b + SvB_b + log(alpha_255 . beta_255) -----------
__global__ void combine_kernel(const unsigned char* __restrict__ ws, float* __restrict__ out) {
    __shared__ float acc8[8];
    const int tid = threadIdx.x;
    const int c  = tid >> 3;
    const int s8 = tid & 7;
    const float* A = (const float*)(ws + WS_ALPHA) + (size_t)c * CC;
    const float* B = (const float*)(ws + WS_BETA)  + (size_t)c * CC;
    float d = 0.0f;
    for (int i = s8; i < CC; i += 8) d += A[i] * B[i];
    d += __shfl_xor(d, 1);
    d += __shfl_xor(d, 2);
    d += __shfl_xor(d, 4);
    float v = 0.0f;
    if (s8 == 0)
        v = ((const float*)(ws + WS_SVA))[c] + ((const float*)(ws + WS_SVB))[c] + __logf(d);
    for (int off = 32; off > 0; off >>= 1) v += __shfl_down(v, off);
    if ((tid & 63) == 0) acc8[tid >> 6] = v;
    __syncthreads();
    if (tid == 0) {
        float s = 0.0f;
        for (int i = 0; i < 8; ++i) s += acc8[i];
        out[0] = (s - *(const float*)(ws + WS_SCORE)) * (1.0f / 64.0f);
    }
}

extern "C" void kernel_launch(void* const* d_in, const int* in_sizes, int n_in,
                              void* d_out, int out_size, void* d_ws, size_t ws_size,
                              hipStream_t stream) {
    const float* emit   = (const float*)d_in[0];
    const int*   target = (const int*)d_in[1];
    const void*  maskp  = d_in[2];
    const float* trans  = (const float*)d_in[3];
    const float* tfs    = (const float*)d_in[4];
    const float* t2e    = (const float*)d_in[5];
    unsigned char* ws   = (unsigned char*)d_ws;
    float* out          = (float*)d_out;

    prep_kernel<<<256, 256, 0, stream>>>(trans, ws);
    crf_scan_kernel<<<40, 512, 0, stream>>>(emit, target, maskp, trans, tfs, t2e, ws);
    combine_kernel<<<1, 512, 0, stream>>>(ws, out);
}